// Round 3
// baseline (663.455 us; speedup 1.0000x reference)
//
#include <hip/hip_runtime.h>
#include <hip/hip_bf16.h>

// ---------------------------------------------------------------------------
// BipartiteGConv:
//   rhs = input @ Wi + bi                [N_IN,64]
//   lhs = other @ Wo                     [N_OT,64]
//   msg_e = leaky_relu(rhs[rj]+lhs[lj]+w_e*We)
//   S[i]  = segment_sum(msg_e, rj)       [N_IN,64]   (activation only!)
//   out   = S @ Wf + cnt*bf              (linearity of segment_sum)
//   res   = S @ (Wf@WoutA) + cnt*(bf@WoutA) + input @ WoutB + bout
// ---------------------------------------------------------------------------

// Y[row] = X[row] @ W (+ b), one wave per row, W staged in LDS.
__global__ void rowgemm64(const float* __restrict__ X, const float* __restrict__ W,
                          const float* __restrict__ b, float* __restrict__ Y, int N) {
    __shared__ float Ws[64 * 64];
    for (int i = threadIdx.x; i < 4096; i += blockDim.x) Ws[i] = W[i];
    __syncthreads();
    const int lane = threadIdx.x & 63;
    const int wid  = threadIdx.x >> 6;
    const int wpb  = blockDim.x >> 6;
    const float bv = b ? b[lane] : 0.0f;
    for (int row = blockIdx.x * wpb + wid; row < N; row += gridDim.x * wpb) {
        float xv  = X[(size_t)row * 64 + lane];
        float acc = bv;
#pragma unroll
        for (int k = 0; k < 64; ++k) {
            float xk = __shfl(xv, k);
            acc = fmaf(xk, Ws[k * 64 + lane], acc);
        }
        Y[(size_t)row * 64 + lane] = acc;
    }
}

// Wcomb = Wf @ WoutA  (64x64), bcomb = bf @ WoutA (64). WoutA = Wout rows 0..63.
__global__ void combine_w(const float* __restrict__ Wf, const float* __restrict__ bf,
                          const float* __restrict__ WoutA, float* __restrict__ Wcomb,
                          float* __restrict__ bcomb) {
    int id = blockIdx.x * blockDim.x + threadIdx.x;
    if (id < 4096) {
        int k = id >> 6, d = id & 63;
        float acc = 0.f;
#pragma unroll 8
        for (int j = 0; j < 64; ++j) acc = fmaf(Wf[k * 64 + j], WoutA[j * 64 + d], acc);
        Wcomb[id] = acc;
    } else if (id < 4160) {
        int d = id - 4096;
        float acc = 0.f;
#pragma unroll 8
        for (int j = 0; j < 64; ++j) acc = fmaf(bf[j], WoutA[j * 64 + d], acc);
        bcomb[d] = acc;
    }
}

// One wave per edge: gather, edge embed, leaky_relu, scatter-add into S.
__global__ void edge_kernel(const float* __restrict__ rhs, const float* __restrict__ lhs,
                            const int* __restrict__ rj, const int* __restrict__ lj,
                            const float* __restrict__ wts, const float* __restrict__ We,
                            float* __restrict__ S, float* __restrict__ cnt, int E) {
    const int lane = threadIdx.x & 63;
    const int e = blockIdx.x * (blockDim.x >> 6) + (threadIdx.x >> 6);
    if (e >= E) return;
    const int r = rj[e];
    const int l = lj[e];
    const float w = wts[e];
    float m = rhs[(size_t)r * 64 + lane] + lhs[(size_t)l * 64 + lane] + w * We[lane];
    float a = (m >= 0.f) ? m : 0.01f * m;
    unsafeAtomicAdd(&S[(size_t)r * 64 + lane], a);
    if (lane == 0) unsafeAtomicAdd(&cnt[r], 1.0f);
}

// res[row] = S[row]@Wcomb + cnt[row]*bcomb + input[row]@WoutB + bout
__global__ void final_kernel(const float* __restrict__ S, const float* __restrict__ cnt,
                             const float* __restrict__ input,
                             const float* __restrict__ Wcomb, const float* __restrict__ bcomb,
                             const float* __restrict__ WoutB, const float* __restrict__ bout,
                             float* __restrict__ out, int N) {
    __shared__ float WcS[4096];
    __shared__ float WbS[4096];
    for (int i = threadIdx.x; i < 4096; i += blockDim.x) {
        WcS[i] = Wcomb[i];
        WbS[i] = WoutB[i];
    }
    __syncthreads();
    const int lane = threadIdx.x & 63;
    const int wid  = threadIdx.x >> 6;
    const int wpb  = blockDim.x >> 6;
    const float bc = bcomb[lane];
    const float bo = bout[lane];
    for (int row = blockIdx.x * wpb + wid; row < N; row += gridDim.x * wpb) {
        float sv = S[(size_t)row * 64 + lane];
        float iv = input[(size_t)row * 64 + lane];
        float acc = fmaf(cnt[row], bc, bo);
#pragma unroll
        for (int k = 0; k < 64; ++k) {
            acc = fmaf(__shfl(sv, k), WcS[k * 64 + lane], acc);
            acc = fmaf(__shfl(iv, k), WbS[k * 64 + lane], acc);
        }
        out[(size_t)row * 64 + lane] = acc;
    }
}

extern "C" void kernel_launch(void* const* d_in, const int* in_sizes, int n_in,
                              void* d_out, int out_size, void* d_ws, size_t ws_size,
                              hipStream_t stream) {
    const float* input = (const float*)d_in[0];
    const float* other = (const float*)d_in[1];
    const int*   rj    = (const int*)d_in[2];
    const int*   lj    = (const int*)d_in[3];
    const float* wts   = (const float*)d_in[4];
    const float* Wi    = (const float*)d_in[5];
    const float* bi    = (const float*)d_in[6];
    const float* Wo    = (const float*)d_in[7];
    const float* We    = (const float*)d_in[8];
    const float* Wf    = (const float*)d_in[9];
    const float* bf    = (const float*)d_in[10];
    const float* Wout  = (const float*)d_in[11];
    const float* bout  = (const float*)d_in[12];
    float* out = (float*)d_out;

    const int N_IN = in_sizes[0] / 64;
    const int N_OT = in_sizes[1] / 64;
    const int E    = in_sizes[2];

    char* ws = (char*)d_ws;
    float* rhs = (float*)ws;   ws += (size_t)N_IN * 64 * sizeof(float);
    float* lhs = (float*)ws;   ws += (size_t)N_OT * 64 * sizeof(float);
    float* S   = (float*)ws;   ws += (size_t)N_IN * 64 * sizeof(float);
    float* cnt = (float*)ws;   ws += (size_t)N_IN * sizeof(float);
    float* Wcomb = (float*)ws; ws += 4096 * sizeof(float);
    float* bcomb = (float*)ws; ws += 64 * sizeof(float);

    // S and cnt are contiguous: zero both with one async memset (graph-capturable).
    hipMemsetAsync(S, 0, ((size_t)N_IN * 64 + N_IN) * sizeof(float), stream);

    rowgemm64<<<2048, 256, 0, stream>>>(input, Wi, bi, rhs, N_IN);
    rowgemm64<<<2048, 256, 0, stream>>>(other, Wo, nullptr, lhs, N_OT);
    combine_w<<<17, 256, 0, stream>>>(Wf, bf, Wout, Wcomb, bcomb);
    edge_kernel<<<(E + 3) / 4, 256, 0, stream>>>(rhs, lhs, rj, lj, wts, We, S, cnt, E);
    final_kernel<<<2048, 256, 0, stream>>>(S, cnt, input, Wcomb, bcomb,
                                           Wout + 64 * 64, bout, out, N_IN);
}

// Round 4
// 540.990 us; speedup vs baseline: 1.2264x; 1.2264x over previous
//
#include <hip/hip_runtime.h>
#include <hip/hip_bf16.h>

// ---------------------------------------------------------------------------
// BipartiteGConv:
//   rhs = input @ Wi + bi                [N_IN,64]   (stored bf16)
//   lhs = other @ Wo                     [N_OT,64]   (stored bf16)
//   msg_e = leaky_relu(rhs[rj]+lhs[lj]+w_e*We)
//   S[i]  = segment_sum(msg_e, rj)       [N_IN,64]   (bf16, pk-atomic accum)
//   res   = S @ (Wf@WoutA) + cnt*(bf@WoutA) + input @ WoutB + bout
//
// R3 profile: edge kernel was atomic-op-throughput bound (64M scalar f32
// atomics = 244 G/s, ~TCC ceiling; VALU 17%, HBM 26%). Fix: pack 2 elems per
// atomic via global_atomic_pk_add_bf16 (32.5M ops) + bf16 gather tables.
// ---------------------------------------------------------------------------

static __device__ __forceinline__ float bf2f(unsigned u) {
    return __uint_as_float(u << 16);
}
static __device__ __forceinline__ unsigned f2bf(float f) {  // round-to-nearest-even
    unsigned u = __float_as_uint(f);
    return (u + 0x7fffu + ((u >> 16) & 1u)) >> 16;
}

// Y[row] = X[row] @ W (+ b), one wave per row, W staged in LDS. bf16 output.
__global__ void rowgemm64(const float* __restrict__ X, const float* __restrict__ W,
                          const float* __restrict__ b, __hip_bfloat16* __restrict__ Y,
                          int N) {
    __shared__ float Ws[64 * 64];
    for (int i = threadIdx.x; i < 4096; i += blockDim.x) Ws[i] = W[i];
    __syncthreads();
    const int lane = threadIdx.x & 63;
    const int wid  = threadIdx.x >> 6;
    const int wpb  = blockDim.x >> 6;
    const float bv = b ? b[lane] : 0.0f;
    for (int row = blockIdx.x * wpb + wid; row < N; row += gridDim.x * wpb) {
        float xv  = X[(size_t)row * 64 + lane];
        float acc = bv;
#pragma unroll
        for (int k = 0; k < 64; ++k) {
            float xk = __shfl(xv, k);
            acc = fmaf(xk, Ws[k * 64 + lane], acc);
        }
        unsigned short* yb = (unsigned short*)Y;
        yb[(size_t)row * 64 + lane] = (unsigned short)f2bf(acc);
    }
}

// Wcomb = Wf @ WoutA  (64x64), bcomb = bf @ WoutA (64). WoutA = Wout rows 0..63.
__global__ void combine_w(const float* __restrict__ Wf, const float* __restrict__ bf,
                          const float* __restrict__ WoutA, float* __restrict__ Wcomb,
                          float* __restrict__ bcomb) {
    int id = blockIdx.x * blockDim.x + threadIdx.x;
    if (id < 4096) {
        int k = id >> 6, d = id & 63;
        float acc = 0.f;
#pragma unroll 8
        for (int j = 0; j < 64; ++j) acc = fmaf(Wf[k * 64 + j], WoutA[j * 64 + d], acc);
        Wcomb[id] = acc;
    } else if (id < 4160) {
        int d = id - 4096;
        float acc = 0.f;
#pragma unroll 8
        for (int j = 0; j < 64; ++j) acc = fmaf(bf[j], WoutA[j * 64 + d], acc);
        bcomb[d] = acc;
    }
}

// Half-wave per edge: lanes 0..31 handle 2 consecutive elements each.
// One packed bf16x2 atomic per lane: 32.5M atomics vs 65M scalar.
__global__ void edge_kernel(const unsigned short* __restrict__ rhs,
                            const unsigned short* __restrict__ lhs,
                            const int* __restrict__ rj, const int* __restrict__ lj,
                            const float* __restrict__ wts, const float* __restrict__ We,
                            unsigned short* __restrict__ S, float* __restrict__ cnt,
                            int E) {
    const int lane = threadIdx.x & 63;
    const int sub  = lane >> 5;   // which of 2 edges in this wave
    const int sl   = lane & 31;   // 2-element slot within the row
    const int e = (blockIdx.x * (blockDim.x >> 6) + (threadIdx.x >> 6)) * 2 + sub;
    if (e >= E) return;
    const int r = rj[e];
    const int l = lj[e];
    const float w = wts[e];
    const unsigned rv = *(const unsigned*)(rhs + ((size_t)r * 64 + sl * 2));
    const unsigned lv = *(const unsigned*)(lhs + ((size_t)l * 64 + sl * 2));
    const float2 we2 = *(const float2*)(We + sl * 2);
    float m0 = bf2f(rv & 0xffffu) + bf2f(lv & 0xffffu) + w * we2.x;
    float m1 = bf2f(rv >> 16)     + bf2f(lv >> 16)     + w * we2.y;
    m0 = (m0 >= 0.f) ? m0 : 0.01f * m0;
    m1 = (m1 >= 0.f) ? m1 : 0.01f * m1;
    unsigned packed = f2bf(m0) | (f2bf(m1) << 16);
    unsigned short* p = S + ((size_t)r * 64 + sl * 2);
    asm volatile("global_atomic_pk_add_bf16 %0, %1, off"
                 :: "v"(p), "v"(packed) : "memory");
    if (sl == 0) unsafeAtomicAdd(&cnt[r], 1.0f);
}

// res[row] = S[row]@Wcomb + cnt[row]*bcomb + input[row]@WoutB + bout
__global__ void final_kernel(const unsigned short* __restrict__ S,
                             const float* __restrict__ cnt,
                             const float* __restrict__ input,
                             const float* __restrict__ Wcomb, const float* __restrict__ bcomb,
                             const float* __restrict__ WoutB, const float* __restrict__ bout,
                             float* __restrict__ out, int N) {
    __shared__ float WcS[4096];
    __shared__ float WbS[4096];
    for (int i = threadIdx.x; i < 4096; i += blockDim.x) {
        WcS[i] = Wcomb[i];
        WbS[i] = WoutB[i];
    }
    __syncthreads();
    const int lane = threadIdx.x & 63;
    const int wid  = threadIdx.x >> 6;
    const int wpb  = blockDim.x >> 6;
    const float bc = bcomb[lane];
    const float bo = bout[lane];
    for (int row = blockIdx.x * wpb + wid; row < N; row += gridDim.x * wpb) {
        float sv = bf2f(S[(size_t)row * 64 + lane]);
        float iv = input[(size_t)row * 64 + lane];
        float acc = fmaf(cnt[row], bc, bo);
#pragma unroll
        for (int k = 0; k < 64; ++k) {
            acc = fmaf(__shfl(sv, k), WcS[k * 64 + lane], acc);
            acc = fmaf(__shfl(iv, k), WbS[k * 64 + lane], acc);
        }
        out[(size_t)row * 64 + lane] = acc;
    }
}

extern "C" void kernel_launch(void* const* d_in, const int* in_sizes, int n_in,
                              void* d_out, int out_size, void* d_ws, size_t ws_size,
                              hipStream_t stream) {
    const float* input = (const float*)d_in[0];
    const float* other = (const float*)d_in[1];
    const int*   rj    = (const int*)d_in[2];
    const int*   lj    = (const int*)d_in[3];
    const float* wts   = (const float*)d_in[4];
    const float* Wi    = (const float*)d_in[5];
    const float* bi    = (const float*)d_in[6];
    const float* Wo    = (const float*)d_in[7];
    const float* We    = (const float*)d_in[8];
    const float* Wf    = (const float*)d_in[9];
    const float* bf    = (const float*)d_in[10];
    const float* Wout  = (const float*)d_in[11];
    const float* bout  = (const float*)d_in[12];
    float* out = (float*)d_out;

    const int N_IN = in_sizes[0] / 64;
    const int N_OT = in_sizes[1] / 64;
    const int E    = in_sizes[2];

    char* ws = (char*)d_ws;
    unsigned short* rhs = (unsigned short*)ws; ws += (size_t)N_IN * 64 * sizeof(unsigned short);
    unsigned short* lhs = (unsigned short*)ws; ws += (size_t)N_OT * 64 * sizeof(unsigned short);
    unsigned short* S   = (unsigned short*)ws; ws += (size_t)N_IN * 64 * sizeof(unsigned short);
    float* cnt   = (float*)ws; ws += (size_t)N_IN * sizeof(float);
    float* Wcomb = (float*)ws; ws += 4096 * sizeof(float);
    float* bcomb = (float*)ws; ws += 64 * sizeof(float);

    // S (bf16) and cnt (f32) are contiguous: zero both with one async memset.
    hipMemsetAsync(S, 0, (size_t)N_IN * 64 * sizeof(unsigned short)
                          + (size_t)N_IN * sizeof(float), stream);

    rowgemm64<<<2048, 256, 0, stream>>>(input, Wi, bi, (__hip_bfloat16*)rhs, N_IN);
    rowgemm64<<<2048, 256, 0, stream>>>(other, Wo, nullptr, (__hip_bfloat16*)lhs, N_OT);
    combine_w<<<17, 256, 0, stream>>>(Wf, bf, Wout, Wcomb, bcomb);
    edge_kernel<<<(E + 7) / 8, 256, 0, stream>>>(rhs, lhs, rj, lj, wts, We, S, cnt, E);
    final_kernel<<<2048, 256, 0, stream>>>(S, cnt, input, Wcomb, bcomb,
                                           Wout + 64 * 64, bout, out, N_IN);
}

// Round 5
// 397.710 us; speedup vs baseline: 1.6682x; 1.3603x over previous
//
#include <hip/hip_runtime.h>
#include <hip/hip_bf16.h>

// ---------------------------------------------------------------------------
// BipartiteGConv, CSR-gather formulation (no fp atomics):
//   rhs = input @ Wi + bi                [N_IN,64]  f32
//   lhs = other @ Wo                     [N_OT,64]  bf16 (gather table)
//   CSR build: deg/hist -> exclusive scan -> scatter (ljp, wp) by dest row
//   S[i] = sum_{e in row i} leaky(rhs[i] + lhs[lj_e] + w_e*We)   (reg accum)
//   res  = S @ (Wf@WoutA) + deg*(bf@WoutA) + input @ WoutB + bout
//
// R4 lesson: wave-per-row GEMMs were LDS-read-bound (128 ds_read/row in
// final). Fix: R=8 row blocking, readlane broadcasts (VALU), 8x fewer LDS ops.
// R3 lesson: edge scatter was atomic-op-bound (244 G/s ceiling) -> CSR.
// ---------------------------------------------------------------------------

static __device__ __forceinline__ float bf2f(unsigned u) {
    return __uint_as_float(u << 16);
}
static __device__ __forceinline__ unsigned f2bf(float f) {  // RNE
    unsigned u = __float_as_uint(f);
    return (u + 0x7fffu + ((u >> 16) & 1u)) >> 16;
}
static __device__ __forceinline__ float bcast(float v, int k) {  // wave broadcast, VALU
    return __int_as_float(__builtin_amdgcn_readlane(__float_as_int(v), k));
}

// Y[row] = X[row] @ W (+ b). R=8 rows per wave iteration; W staged in LDS,
// one ds_read per (k, 8 rows).
template <bool BF16OUT>
__global__ void rowgemm64(const float* __restrict__ X, const float* __restrict__ W,
                          const float* __restrict__ b, void* __restrict__ Y, int N) {
    __shared__ float Ws[4096];
    for (int i = threadIdx.x; i < 4096; i += blockDim.x) Ws[i] = W[i];
    __syncthreads();
    const int lane = threadIdx.x & 63;
    const int wid  = threadIdx.x >> 6;
    const int wpb  = blockDim.x >> 6;
    const float bv = b ? b[lane] : 0.0f;
    const long long wglob = blockIdx.x * wpb + wid;
    const long long wtot  = (long long)gridDim.x * wpb;
    float* Yf = (float*)Y;
    unsigned short* Yb = (unsigned short*)Y;
    for (long long base = wglob * 8; base < N; base += wtot * 8) {
        if (base + 8 <= N) {
            float xv[8], acc[8];
#pragma unroll
            for (int r = 0; r < 8; ++r) {
                xv[r]  = X[(base + r) * 64 + lane];
                acc[r] = bv;
            }
#pragma unroll
            for (int k = 0; k < 64; ++k) {
                float wv = Ws[k * 64 + lane];
#pragma unroll
                for (int r = 0; r < 8; ++r) acc[r] = fmaf(bcast(xv[r], k), wv, acc[r]);
            }
#pragma unroll
            for (int r = 0; r < 8; ++r) {
                if (BF16OUT) Yb[(base + r) * 64 + lane] = (unsigned short)f2bf(acc[r]);
                else         Yf[(base + r) * 64 + lane] = acc[r];
            }
        } else {
            for (long long row = base; row < N; ++row) {
                float xv = X[row * 64 + lane], acc = bv;
#pragma unroll
                for (int k = 0; k < 64; ++k)
                    acc = fmaf(bcast(xv, k), Ws[k * 64 + lane], acc);
                if (BF16OUT) Yb[row * 64 + lane] = (unsigned short)f2bf(acc);
                else         Yf[row * 64 + lane] = acc;
            }
        }
    }
}

// Wcomb = Wf @ WoutA (64x64), bcomb = bf @ WoutA (64). WoutA = Wout rows 0..63.
__global__ void combine_w(const float* __restrict__ Wf, const float* __restrict__ bf,
                          const float* __restrict__ WoutA, float* __restrict__ Wcomb,
                          float* __restrict__ bcomb) {
    int id = blockIdx.x * blockDim.x + threadIdx.x;
    if (id < 4096) {
        int k = id >> 6, d = id & 63;
        float acc = 0.f;
#pragma unroll 8
        for (int j = 0; j < 64; ++j) acc = fmaf(Wf[k * 64 + j], WoutA[j * 64 + d], acc);
        Wcomb[id] = acc;
    } else if (id < 4160) {
        int d = id - 4096;
        float acc = 0.f;
#pragma unroll 8
        for (int j = 0; j < 64; ++j) acc = fmaf(bf[j], WoutA[j * 64 + d], acc);
        bcomb[d] = acc;
    }
}

// --- CSR build ---
__global__ void hist_kernel(const int* __restrict__ rj, int* __restrict__ deg, int E) {
    int i = blockIdx.x * blockDim.x + threadIdx.x, st = gridDim.x * blockDim.x;
    for (; i < E; i += st) atomicAdd(&deg[rj[i]], 1);
}

// Block-local exclusive scan (1024/block), Hillis-Steele in LDS.
__global__ void scan1_kernel(const int* __restrict__ deg, int* __restrict__ rowoff,
                             int* __restrict__ blksum, int N) {
    __shared__ int s[1024];
    const int tid = threadIdx.x;
    const int i = blockIdx.x * 1024 + tid;
    int v = (i < N) ? deg[i] : 0;
    s[tid] = v;
    __syncthreads();
    for (int off = 1; off < 1024; off <<= 1) {
        int t = (tid >= off) ? s[tid - off] : 0;
        __syncthreads();
        s[tid] += t;
        __syncthreads();
    }
    if (i < N) rowoff[i] = s[tid] - v;  // exclusive
    if (tid == 1023) blksum[blockIdx.x] = s[1023];
}

// Exclusive scan of block sums (nb <= 1024), in place.
__global__ void scan2_kernel(int* __restrict__ blksum, int nb) {
    __shared__ int s[1024];
    const int tid = threadIdx.x;
    int v = (tid < nb) ? blksum[tid] : 0;
    s[tid] = v;
    __syncthreads();
    for (int off = 1; off < 1024; off <<= 1) {
        int t = (tid >= off) ? s[tid - off] : 0;
        __syncthreads();
        s[tid] += t;
        __syncthreads();
    }
    if (tid < nb) blksum[tid] = s[tid] - v;
}

__global__ void scan3_kernel(int* __restrict__ rowoff, const int* __restrict__ blksum,
                             int* __restrict__ cursor, int N, int E) {
    int i = blockIdx.x * blockDim.x + threadIdx.x, st = gridDim.x * blockDim.x;
    for (; i < N; i += st) {
        int v = rowoff[i] + blksum[i >> 10];
        rowoff[i] = v;
        cursor[i] = v;
    }
    if (blockIdx.x == 0 && threadIdx.x == 0) rowoff[N] = E;
}

// Scatter edge payloads into CSR order: ljp[pos], wp[pos].
__global__ void scatter_kernel(const int* __restrict__ rj, const int* __restrict__ lj,
                               const float* __restrict__ wts, int* __restrict__ cursor,
                               int* __restrict__ ljp, float* __restrict__ wp, int E) {
    int i = blockIdx.x * blockDim.x + threadIdx.x, st = gridDim.x * blockDim.x;
    for (; i < E; i += st) {
        int r = rj[i];
        int pos = atomicAdd(&cursor[r], 1);
        ljp[pos] = lj[i];
        wp[pos]  = wts[i];
    }
}

// One wave per output row: register-accumulate leaky(rhs + lhs[l] + w*We).
// 4-deep software pipeline to keep gathers in flight. No atomics.
__global__ void reduce_kernel(const float* __restrict__ rhs,
                              const unsigned short* __restrict__ lhs,
                              const int* __restrict__ ljp, const float* __restrict__ wp,
                              const float* __restrict__ We, const int* __restrict__ rowoff,
                              float* __restrict__ S, int N) {
    const int lane = threadIdx.x & 63;
    const int wid  = threadIdx.x >> 6;
    const int wpb  = blockDim.x >> 6;
    const float wev = We[lane];
    for (int row = blockIdx.x * wpb + wid; row < N; row += gridDim.x * wpb) {
        const int beg = rowoff[row], end = rowoff[row + 1];
        const float rv = rhs[(size_t)row * 64 + lane];
        float acc = 0.f;
        int idx = beg;
        for (; idx + 4 <= end; idx += 4) {
            int l0 = ljp[idx], l1 = ljp[idx + 1], l2 = ljp[idx + 2], l3 = ljp[idx + 3];
            float w0 = wp[idx], w1 = wp[idx + 1], w2 = wp[idx + 2], w3 = wp[idx + 3];
            float a0 = bf2f(lhs[(size_t)l0 * 64 + lane]);
            float a1 = bf2f(lhs[(size_t)l1 * 64 + lane]);
            float a2 = bf2f(lhs[(size_t)l2 * 64 + lane]);
            float a3 = bf2f(lhs[(size_t)l3 * 64 + lane]);
            float m0 = rv + a0 + w0 * wev;
            float m1 = rv + a1 + w1 * wev;
            float m2 = rv + a2 + w2 * wev;
            float m3 = rv + a3 + w3 * wev;
            acc += (m0 >= 0.f) ? m0 : 0.01f * m0;
            acc += (m1 >= 0.f) ? m1 : 0.01f * m1;
            acc += (m2 >= 0.f) ? m2 : 0.01f * m2;
            acc += (m3 >= 0.f) ? m3 : 0.01f * m3;
        }
        for (; idx < end; ++idx) {
            int l = ljp[idx];
            float w = wp[idx];
            float a = bf2f(lhs[(size_t)l * 64 + lane]);
            float m = rv + a + w * wev;
            acc += (m >= 0.f) ? m : 0.01f * m;
        }
        S[(size_t)row * 64 + lane] = acc;
    }
}

// res[row] = S[row]@Wcomb + deg[row]*bcomb + input[row]@WoutB + bout. R=8.
__global__ void final_kernel(const float* __restrict__ S, const int* __restrict__ rowoff,
                             const float* __restrict__ input,
                             const float* __restrict__ Wcomb, const float* __restrict__ bcomb,
                             const float* __restrict__ WoutB, const float* __restrict__ bout,
                             float* __restrict__ out, int N) {
    __shared__ float WcS[4096];
    __shared__ float WbS[4096];
    for (int i = threadIdx.x; i < 4096; i += blockDim.x) {
        WcS[i] = Wcomb[i];
        WbS[i] = WoutB[i];
    }
    __syncthreads();
    const int lane = threadIdx.x & 63;
    const int wid  = threadIdx.x >> 6;
    const int wpb  = blockDim.x >> 6;
    const float bc = bcomb[lane];
    const float bo = bout[lane];
    const long long wglob = blockIdx.x * wpb + wid;
    const long long wtot  = (long long)gridDim.x * wpb;
    for (long long base = wglob * 8; base < N; base += wtot * 8) {
        if (base + 8 <= N) {
            float sv[8], iv[8], acc[8];
#pragma unroll
            for (int r = 0; r < 8; ++r) {
                sv[r] = S[(base + r) * 64 + lane];
                iv[r] = input[(base + r) * 64 + lane];
                float cnt = (float)(rowoff[base + r + 1] - rowoff[base + r]);
                acc[r] = fmaf(cnt, bc, bo);
            }
#pragma unroll
            for (int k = 0; k < 64; ++k) {
                float wc = WcS[k * 64 + lane];
                float wb = WbS[k * 64 + lane];
#pragma unroll
                for (int r = 0; r < 8; ++r) {
                    acc[r] = fmaf(bcast(sv[r], k), wc, acc[r]);
                    acc[r] = fmaf(bcast(iv[r], k), wb, acc[r]);
                }
            }
#pragma unroll
            for (int r = 0; r < 8; ++r) out[(base + r) * 64 + lane] = acc[r];
        } else {
            for (long long row = base; row < N; ++row) {
                float sv = S[row * 64 + lane];
                float iv = input[row * 64 + lane];
                float cnt = (float)(rowoff[row + 1] - rowoff[row]);
                float acc = fmaf(cnt, bc, bo);
#pragma unroll
                for (int k = 0; k < 64; ++k) {
                    acc = fmaf(bcast(sv, k), WcS[k * 64 + lane], acc);
                    acc = fmaf(bcast(iv, k), WbS[k * 64 + lane], acc);
                }
                out[row * 64 + lane] = acc;
            }
        }
    }
}

extern "C" void kernel_launch(void* const* d_in, const int* in_sizes, int n_in,
                              void* d_out, int out_size, void* d_ws, size_t ws_size,
                              hipStream_t stream) {
    const float* input = (const float*)d_in[0];
    const float* other = (const float*)d_in[1];
    const int*   rj    = (const int*)d_in[2];
    const int*   lj    = (const int*)d_in[3];
    const float* wts   = (const float*)d_in[4];
    const float* Wi    = (const float*)d_in[5];
    const float* bi    = (const float*)d_in[6];
    const float* Wo    = (const float*)d_in[7];
    const float* We    = (const float*)d_in[8];
    const float* Wf    = (const float*)d_in[9];
    const float* bf    = (const float*)d_in[10];
    const float* Wout  = (const float*)d_in[11];
    const float* bout  = (const float*)d_in[12];
    float* out = (float*)d_out;

    const int N_IN = in_sizes[0] / 64;
    const int N_OT = in_sizes[1] / 64;
    const int E    = in_sizes[2];
    const int nb1  = (N_IN + 1023) / 1024;

    char* ws = (char*)d_ws;
    float* rhs   = (float*)ws; ws += (size_t)N_IN * 64 * sizeof(float);
    float* S     = (float*)ws; ws += (size_t)N_IN * 64 * sizeof(float);
    float* wp    = (float*)ws; ws += (size_t)E * sizeof(float);
    float* Wcomb = (float*)ws; ws += 4096 * sizeof(float);
    float* bcomb = (float*)ws; ws += 64 * sizeof(float);
    int* deg     = (int*)ws;   ws += (size_t)N_IN * sizeof(int);
    int* rowoff  = (int*)ws;   ws += ((size_t)N_IN + 1) * sizeof(int);
    int* cursor  = (int*)ws;   ws += (size_t)N_IN * sizeof(int);
    int* blksum  = (int*)ws;   ws += 1024 * sizeof(int);
    int* ljp     = (int*)ws;   ws += (size_t)E * sizeof(int);
    unsigned short* lhs = (unsigned short*)ws; ws += (size_t)N_OT * 64 * sizeof(unsigned short);

    hipMemsetAsync(deg, 0, (size_t)N_IN * sizeof(int), stream);

    rowgemm64<false><<<2048, 256, 0, stream>>>(input, Wi, bi, rhs, N_IN);
    rowgemm64<true ><<<1024, 256, 0, stream>>>(other, Wo, nullptr, lhs, N_OT);
    combine_w<<<17, 256, 0, stream>>>(Wf, bf, Wout, Wcomb, bcomb);

    hist_kernel<<<1024, 256, 0, stream>>>(rj, deg, E);
    scan1_kernel<<<nb1, 1024, 0, stream>>>(deg, rowoff, blksum, N_IN);
    scan2_kernel<<<1, 1024, 0, stream>>>(blksum, nb1);
    scan3_kernel<<<256, 256, 0, stream>>>(rowoff, blksum, cursor, N_IN, E);
    scatter_kernel<<<1024, 256, 0, stream>>>(rj, lj, wts, cursor, ljp, wp, E);

    reduce_kernel<<<2048, 256, 0, stream>>>(rhs, lhs, ljp, wp, We, rowoff, S, N_IN);
    final_kernel<<<2048, 256, 0, stream>>>(S, rowoff, input, Wcomb, bcomb,
                                           Wout + 64 * 64, bout, out, N_IN);
}